// Round 10
// baseline (749.736 us; speedup 1.0000x reference)
//
#include <hip/hip_runtime.h>
#include <hip/hip_bf16.h>

typedef __bf16 bf16_t;
typedef __bf16 bf16x8 __attribute__((ext_vector_type(8)));
typedef float f32x4 __attribute__((ext_vector_type(4)));
typedef int   i32x4 __attribute__((ext_vector_type(4)));

#define SEQLEN 256
#define NBATCH 64
#define INDIM  512
#define HID    1024
#define NBLK   256

// workspace layout (bytes) — total ~63.3 MB
#define XF_OFF   0ull            // bf16 [256][32768]  = 16777216  (x fragments)
#define WXF_OFF  16777216ull     // bf16 [128][16384]  = 4194304   (W_i fragments per col-block)
#define WHF_OFF  20971520ull     // bf16 [128][32768]  = 8388608   (W_h fragments per col-block)
#define BS_OFF   29360128ull     // f32  [4096]        = 16384     (bias sums)
#define HSEQ_OFF 29376512ull     // bf16 [257][65536]  = 33685504  (write-once h slots = h history)
#define FLG_OFF  63062016ull     // int  [257][256]    = 263168    (per-step per-block ready flags)
#define SLOT_BYTES 131072ull
#define SLOT_ELEMS 65536

__device__ __forceinline__ bf16x8 cvt8(float4 a, float4 b) {
  bf16x8 v;
  v[0] = (bf16_t)a.x; v[1] = (bf16_t)a.y; v[2] = (bf16_t)a.z; v[3] = (bf16_t)a.w;
  v[4] = (bf16_t)b.x; v[5] = (bf16_t)b.y; v[6] = (bf16_t)b.z; v[7] = (bf16_t)b.w;
  return v;
}

// ---------------- pack x -> bf16 MFMA A-fragment order ----------------
__global__ __launch_bounds__(256) void pack_xf_k(const float* __restrict__ x,
                                                 bf16_t* __restrict__ xf) {
  int idx = blockIdx.x * 256 + threadIdx.x;     // 1,048,576 chunks of 8
  int t = idx >> 12;
  int r = idx & 4095;
  int batch = r >> 6, c8 = r & 63;
  const float4* s = (const float4*)(x + ((size_t)t * NBATCH + batch) * INDIM + c8 * 8);
  int kk = c8 >> 2, lhi = c8 & 3;
  int kh = kk >> 3, kkl = kk & 7;
  int bg = batch >> 4, lane = (batch & 15) + 16 * lhi;
  bf16_t* d = xf + (size_t)t * 32768 + (size_t)(((bg * 2 + kh) * 8 + kkl) * 64 + lane) * 8;
  *(bf16x8*)d = cvt8(s[0], s[1]);
}

// ---------------- pack weights (B-fragment order) + bias sums ----------------
struct GatePtrs {
  const float* Wi[4];
  const float* bi[4];
  const float* Wh[4];
  const float* bh[4];
};

__global__ __launch_bounds__(256) void pack_w_k(GatePtrs p,
                                                bf16_t* __restrict__ Wxf,
                                                bf16_t* __restrict__ Whf,
                                                float* __restrict__ bsum) {
  int idx = blockIdx.x * 256 + threadIdx.x;       // 0 .. 786431
  int row = idx / 192;                            // packed row, 0..4095
  int c   = idx % 192;
  int blk = row >> 5, r32 = row & 31, g = r32 >> 3, jj = r32 & 7;
  int j = blk * 8 + jj;                           // original hidden index
  int g2 = r32 >> 4, lrow = r32 & 15;
  if (c == 0) bsum[row] = p.bi[g][j] + p.bh[g][j];
  if (c < 64) {                                   // W_i row j, k-chunk c
    const float4* s = (const float4*)(p.Wi[g] + (size_t)j * INDIM + c * 8);
    int kk = c >> 2, lane = lrow + 16 * (c & 3);
    *(bf16x8*)(Wxf + (size_t)blk * 16384 + (size_t)((kk * 2 + g2) * 64 + lane) * 8) = cvt8(s[0], s[1]);
  } else {                                        // W_h row j, k-chunk cc
    int cc = c - 64;
    const float4* s = (const float4*)(p.Wh[g] + (size_t)j * HID + cc * 8);
    int kk = cc >> 2, lane = lrow + 16 * (cc & 3);
    *(bf16x8*)(Whf + (size_t)blk * 32768 + (size_t)((kk * 2 + g2) * 64 + lane) * 8) = cvt8(s[0], s[1]);
  }
}

// ---------------- finalize: fragment-order bf16 h slots -> coalesced fp32 out ----------------
// idx -> (t 0..256, batch, j-chunk); t==256 writes h_fin (slot 256, same region formula).
__global__ __launch_bounds__(256) void finalize_k(const bf16_t* __restrict__ hseq,
                                                  float* __restrict__ out) {
  int idx = blockIdx.x * 256 + threadIdx.x;   // 257*64*128 = 2,105,344
  int c = idx & 127;
  int batch = (idx >> 7) & 63;
  int t = idx >> 13;
  int slot = (t < 256) ? (t + 1) : 256;
  int j0 = c * 8;
  int kkg = j0 >> 5;
  int sub = (j0 & 31) >> 3;
  int lane = (batch & 15) + 16 * sub;
  int bg2 = (batch >> 4) * 2 + (kkg >> 4);
  const bf16_t* src = hseq + (size_t)slot * SLOT_ELEMS + (size_t)((bg2 * 16 + (kkg & 15)) * 64 + lane) * 8;
  bf16x8 v = *(const bf16x8*)src;
  float* d = out + ((size_t)t * NBATCH + batch) * HID + j0;
  *(float4*)d       = make_float4((float)v[0], (float)v[1], (float)v[2], (float)v[3]);
  *(float4*)(d + 4) = make_float4((float)v[4], (float)v[5], (float)v[6], (float)v[7]);
}

// forced plain-cacheable loads (issue pinned by asm; completion via explicit s_waitcnt)
#define PLDC(dst, ptr, OFF) \
  asm volatile("global_load_dwordx4 %0, %1, off offset:" OFF : "=v"(dst) : "v"(ptr))

// ---------------- persistent dataflow recurrence ----------------
// 256 blocks x 256 threads (4 waves). Block b: cb = b&127 owns h cols [cb*8,+8);
// bgs = b>>7 owns batches [32bgs,+32). Wave w: bhalf = w>>1, kh = w&1.
// W_h fragments in VGPR/AGPR (loaded once); W_i fragments in LDS. No out stores in the
// loop (h history lives in the write-once slots; finalize_k transposes afterwards).
// Per step: issue x loads + flag load -> vmcnt(1) -> x-part MFMA (hidden under flag RT)
// -> vmcnt(0) -> poll retry -> issue h loads -> vmcnt(0) -> reg-only h-MFMA -> accbuf
// -> barrier -> elementwise -> publish (WT dword atomics) -> barrier(drain) -> flag.
__global__ __launch_bounds__(256, 1) void lstm_rec_k(const bf16_t* __restrict__ Whf,
                                                     const bf16_t* __restrict__ Wxf,
                                                     const bf16_t* __restrict__ xf,
                                                     const float* __restrict__ bsum,
                                                     bf16_t* __restrict__ hseq,
                                                     int* __restrict__ flags,
                                                     float* __restrict__ out) {
  const int b = blockIdx.x;
  const int cb = b & 127, bgs = b >> 7;
  const int tid = threadIdx.x;
  const int w = tid >> 6, l = tid & 63;
  const int bhalf = w >> 1, kh = w & 1;
  const int bg = bgs * 2 + bhalf;

  __shared__ bf16_t xwlds[16384];       // 32 KB: W_i fragments
  __shared__ float  accbuf[2][32][36];  // 9 KB: [kh][gate-row][local batch32 + pad]

  // --- W_i fragments -> LDS (coalesced DMA) ---
#pragma unroll
  for (int i = 0; i < 8; ++i)
    __builtin_amdgcn_global_load_lds((const __attribute__((address_space(1))) void*)(Wxf + (size_t)cb * 16384 + (i * 256 + tid) * 8),
                                     (__attribute__((address_space(3))) void*)(xwlds + (i * 256 + tid) * 8),
                                     16, 0, 0);

  // --- W_h fragments -> registers (32 x dwordx4 asm loads, loop-invariant) ---
  i32x4 whr[16][2];
  {
    const char* wb = (const char*)Whf + (size_t)cb * 65536 + (size_t)(kh * 32768) + (size_t)l * 16;
    const char* w0 = wb;          const char* w1 = wb + 4096;
    const char* w2 = wb + 8192;   const char* w3 = wb + 12288;
    const char* w4 = wb + 16384;  const char* w5 = wb + 20480;
    const char* w6 = wb + 24576;  const char* w7 = wb + 28672;
    PLDC(whr[0][0],  w0, "0"); PLDC(whr[0][1],  w0, "1024"); PLDC(whr[1][0],  w0, "2048"); PLDC(whr[1][1],  w0, "3072");
    PLDC(whr[2][0],  w1, "0"); PLDC(whr[2][1],  w1, "1024"); PLDC(whr[3][0],  w1, "2048"); PLDC(whr[3][1],  w1, "3072");
    PLDC(whr[4][0],  w2, "0"); PLDC(whr[4][1],  w2, "1024"); PLDC(whr[5][0],  w2, "2048"); PLDC(whr[5][1],  w2, "3072");
    PLDC(whr[6][0],  w3, "0"); PLDC(whr[6][1],  w3, "1024"); PLDC(whr[7][0],  w3, "2048"); PLDC(whr[7][1],  w3, "3072");
    PLDC(whr[8][0],  w4, "0"); PLDC(whr[8][1],  w4, "1024"); PLDC(whr[9][0],  w4, "2048"); PLDC(whr[9][1],  w4, "3072");
    PLDC(whr[10][0], w5, "0"); PLDC(whr[10][1], w5, "1024"); PLDC(whr[11][0], w5, "2048"); PLDC(whr[11][1], w5, "3072");
    PLDC(whr[12][0], w6, "0"); PLDC(whr[12][1], w6, "1024"); PLDC(whr[13][0], w6, "2048"); PLDC(whr[13][1], w6, "3072");
    PLDC(whr[14][0], w7, "0"); PLDC(whr[14][1], w7, "1024"); PLDC(whr[15][0], w7, "2048"); PLDC(whr[15][1], w7, "3072");
  }
  asm volatile("s_waitcnt vmcnt(0)" ::: "memory");
  __builtin_amdgcn_sched_barrier(0);

  // elementwise ownership: local batch eb = tid>>3, col ejj = tid&7
  const int eb = tid >> 3, ejj = tid & 7;
  const int gb = bgs * 32 + eb;
  const int j  = cb * 8 + ejj;
  const int p_lane = (gb & 15) + 16 * ((j & 31) >> 3);
  const int p_kkg = j >> 5;
  const size_t pub_off = (size_t)((((gb >> 4) * 2 + (p_kkg >> 4)) * 16 + (p_kkg & 15)) * 64 + p_lane) * 16
                       + (size_t)(j & 7) * 2;
  const float bsF = bsum[cb * 32 + ejj];
  const float bsI = bsum[cb * 32 + 8 + ejj];
  const float bsO = bsum[cb * 32 + 16 + ejj];
  const float bsC = bsum[cb * 32 + 24 + ejj];
  float cs = 0.f;

  const size_t pollbase = (size_t)((bg * 2 + kh) * 16) * 1024 + (size_t)l * 16;
  const char* fbase = (const char*)flags + (size_t)l * 16;

  __syncthreads();   // xwlds DMA complete

  for (int t = 0; t < SEQLEN; ++t) {
    // ---- 1. issue x loads, then the flag load (newest in vmcnt FIFO) ----
    const char* xp0 = (const char*)xf + (size_t)t * 65536 + (size_t)((bg * 2 + kh) * 8 * 64 + l) * 16;
    const char* xp1 = xp0 + 4096;
    i32x4 xr[8];
    PLDC(xr[0], xp0, "0"); PLDC(xr[1], xp0, "1024"); PLDC(xr[2], xp0, "2048"); PLDC(xr[3], xp0, "3072");
    PLDC(xr[4], xp1, "0"); PLDC(xr[5], xp1, "1024"); PLDC(xr[6], xp1, "2048"); PLDC(xr[7], xp1, "3072");
    const char* fp = fbase + (size_t)t * 1024;
    i32x4 f;
    asm volatile("global_load_dwordx4 %0, %1, off sc0 sc1" : "=v"(f) : "v"(fp));

    // ---- 2. x-part MFMA under the flag-load RT (vmcnt(1): x retired, flag in flight) ----
    asm volatile("s_waitcnt vmcnt(1)" ::: "memory");
    __builtin_amdgcn_sched_barrier(0);
    f32x4 acc0 = {}, acc1 = {};
#pragma unroll
    for (int kkl = 0; kkl < 8; ++kkl) {
      const int kk = kh * 8 + kkl;
      bf16x8 xv = __builtin_bit_cast(bf16x8, xr[kkl]);
      bf16x8 w0 = *(const bf16x8*)(xwlds + (size_t)((kk * 2 + 0) * 64 + l) * 8);
      bf16x8 w1 = *(const bf16x8*)(xwlds + (size_t)((kk * 2 + 1) * 64 + l) * 8);
      acc0 = __builtin_amdgcn_mfma_f32_16x16x32_bf16(xv, w0, acc0, 0, 0, 0);
      acc1 = __builtin_amdgcn_mfma_f32_16x16x32_bf16(xv, w1, acc1, 0, 0, 0);
    }

    // ---- 3. flag check + retry ----
    asm volatile("s_waitcnt vmcnt(0)" ::: "memory");
    __builtin_amdgcn_sched_barrier(0);
    while (__any((f[0] == 0) | (f[1] == 0) | (f[2] == 0) | (f[3] == 0))) {
      __builtin_amdgcn_s_sleep(1);
      asm volatile("global_load_dwordx4 %0, %1, off sc0 sc1" : "=v"(f) : "v"(fp));
      asm volatile("s_waitcnt vmcnt(0)" ::: "memory");
      __builtin_amdgcn_sched_barrier(0);
    }

    // ---- 4. h fragments (plain cacheable; L2-shared within XCD) ----
    const char* q0 = (const char*)hseq + (size_t)t * SLOT_BYTES + pollbase;
    const char* q1 = q0 + 4096;
    const char* q2 = q0 + 8192;
    const char* q3 = q0 + 12288;
    i32x4 hv[16];
    PLDC(hv[0],  q0, "0"); PLDC(hv[1],  q0, "1024"); PLDC(hv[2],  q0, "2048"); PLDC(hv[3],  q0, "3072");
    PLDC(hv[4],  q1, "0"); PLDC(hv[5],  q1, "1024"); PLDC(hv[6],  q1, "2048"); PLDC(hv[7],  q1, "3072");
    PLDC(hv[8],  q2, "0"); PLDC(hv[9],  q2, "1024"); PLDC(hv[10], q2, "2048"); PLDC(hv[11], q2, "3072");
    PLDC(hv[12], q3, "0"); PLDC(hv[13], q3, "1024"); PLDC(hv[14], q3, "2048"); PLDC(hv[15], q3, "3072");
    asm volatile("s_waitcnt vmcnt(0)" ::: "memory");
    __builtin_amdgcn_sched_barrier(0);

    // ---- 5. h-part: reg-only MFMA (weights resident) ----
#pragma unroll
    for (int kkl = 0; kkl < 16; ++kkl) {
      bf16x8 hf = __builtin_bit_cast(bf16x8, hv[kkl]);
      acc0 = __builtin_amdgcn_mfma_f32_16x16x32_bf16(hf, __builtin_bit_cast(bf16x8, whr[kkl][0]), acc0, 0, 0, 0);
      acc1 = __builtin_amdgcn_mfma_f32_16x16x32_bf16(hf, __builtin_bit_cast(bf16x8, whr[kkl][1]), acc1, 0, 0, 0);
    }

    // D layout: gate-row = g2*16 + (l&15), local batch = bhalf*16 + (l>>4)*4 + reg
    *(f32x4*)&accbuf[kh][l & 15][bhalf * 16 + (l >> 4) * 4]        = acc0;
    *(f32x4*)&accbuf[kh][16 + (l & 15)][bhalf * 16 + (l >> 4) * 4] = acc1;
    __syncthreads();

    // ---- 6. fused elementwise + publish ----
    {
      float pf = bsF + accbuf[0][ejj][eb]      + accbuf[1][ejj][eb];
      float pi = bsI + accbuf[0][8 + ejj][eb]  + accbuf[1][8 + ejj][eb];
      float po = bsO + accbuf[0][16 + ejj][eb] + accbuf[1][16 + ejj][eb];
      float pc = bsC + accbuf[0][24 + ejj][eb] + accbuf[1][24 + ejj][eb];
      float fg = 1.f / (1.f + __expf(-pf));
      float ig = 1.f / (1.f + __expf(-pi));
      float og = 1.f / (1.f + __expf(-po));
      float e2 = __expf(-2.f * fabsf(pc));
      float gg = __builtin_copysignf((1.f - e2) / (1.f + e2), pc);
      cs = fg * cs + ig * gg;
      float e2c = __expf(-2.f * fabsf(cs));
      float th = __builtin_copysignf((1.f - e2c) / (1.f + e2c), cs);
      float hval = og * th;

      unsigned int my = (unsigned int)__builtin_bit_cast(unsigned short, (bf16_t)hval);
      unsigned int other = __shfl_xor(my, 1);
      if (!(tid & 1)) {
        unsigned int pk = my | (other << 16);
        unsigned int* hd = (unsigned int*)((char*)hseq + (size_t)(t + 1) * SLOT_BYTES + pub_off);
        __hip_atomic_store(hd, pk, __ATOMIC_RELAXED, __HIP_MEMORY_SCOPE_AGENT);
      }
      if (t == SEQLEN - 1)   // c_fin only; h_seq/h_fin come from the slots via finalize_k
        out[(size_t)SEQLEN * NBATCH * HID + (size_t)NBATCH * HID + (size_t)gb * HID + j] = cs;
    }

    // ---- 7. release: drain publishes (vmcnt(0) before s_barrier), then flag ----
    __syncthreads();
    if (t < SEQLEN - 1 && tid == 0)
      __hip_atomic_store(&flags[(t + 1) * NBLK + b], 1, __ATOMIC_RELAXED, __HIP_MEMORY_SCOPE_AGENT);
  }
}

extern "C" void kernel_launch(void* const* d_in, const int* in_sizes, int n_in,
                              void* d_out, int out_size, void* d_ws, size_t ws_size,
                              hipStream_t stream) {
  (void)in_sizes; (void)n_in; (void)out_size; (void)ws_size;
  char* ws = (char*)d_ws;
  bf16_t* xf   = (bf16_t*)(ws + XF_OFF);
  bf16_t* Wxf  = (bf16_t*)(ws + WXF_OFF);
  bf16_t* Whf  = (bf16_t*)(ws + WHF_OFF);
  float*  bs   = (float*)(ws + BS_OFF);
  bf16_t* hseq = (bf16_t*)(ws + HSEQ_OFF);
  int*    flg  = (int*)(ws + FLG_OFF);

  const float* x = (const float*)d_in[0];
  GatePtrs p;
  for (int g = 0; g < 4; ++g) {
    p.Wi[g] = (const float*)d_in[1 + 4 * g];
    p.bi[g] = (const float*)d_in[2 + 4 * g];
    p.Wh[g] = (const float*)d_in[3 + 4 * g];
    p.bh[g] = (const float*)d_in[4 + 4 * g];
  }

  pack_xf_k<<<4096, 256, 0, stream>>>(x, xf);
  pack_w_k<<<3072, 256, 0, stream>>>(p, Wxf, Whf, bs);
  hipMemsetAsync(flg, 1, NBLK * 4, stream);                      // t=0 flags: 0x01010101 != 0
  hipMemsetAsync(flg + NBLK, 0, 256 * NBLK * 4, stream);         // t=1..256 flags clear
  hipMemsetAsync(hseq, 0, SLOT_BYTES, stream);                   // slot 0 = h(0) = zeros
  lstm_rec_k<<<NBLK, 256, 0, stream>>>(Whf, Wxf, xf, bs, hseq, flg, (float*)d_out);
  finalize_k<<<8224, 256, 0, stream>>>(hseq, (float*)d_out);
}